// Round 4
// baseline (1487.167 us; speedup 1.0000x reference)
//
#include <hip/hip_runtime.h>
#include <stdint.h>

// out[b, q, n] = softmax_n( fact * S[b, q*8+n] ),  S[b,o] = sum_c ql[c,b,o]*kl[c,o]
//   ql[c,b,o] = sum_h q[c,b,h]*Wq[o,h] + bq[o]
//   kl[c,o]   = sum_d k[c,d]*Wk[o,d] + bk[o]
// A=B=256, H=QD=2048, n=8, fact = 1/16.
//
// R4: eliminate the q f32->bf16 pre-pass (~130us at BW roofline moving 804MB).
// main_kernel reads q f32 DIRECTLY (row slices are 128B-line aligned; XCD
// swizzle keeps each line HBM-fetched once) and reg-stages A: global f32 ->
// 16 VGPR -> bf16 cast -> swizzled ds_write_b128, hidden under the tile's
// MFMAs. BK=32, LDS 64KiB (2xA + 2xB bufs). B (Wq, 8MB) still pre-converted.
// Net q traffic 1072MB -> 536MB. Occupancy is register-bound (acc = 128 AGPR
// + ~116 VGPR = 8 waves/CU) so schedule/tile geometry kept from R3.

typedef __attribute__((ext_vector_type(8))) __bf16 bf16x8;
typedef __attribute__((ext_vector_type(4))) __bf16 bf16x4;
typedef __attribute__((ext_vector_type(4))) float f32x4;

__device__ __forceinline__ void gload_lds16(const void* g, void* l) {
  __builtin_amdgcn_global_load_lds(
      (const __attribute__((address_space(1))) uint32_t*)g,
      (__attribute__((address_space(3))) uint32_t*)l, 16, 0, 0);
}

// ---------------- convert: Wq, Wk, k (f32) -> bf16 (q no longer converted) --
__global__ void convert_kernel(const float* __restrict__ Wq,
                               const float* __restrict__ Wk,
                               const float* __restrict__ kin,
                               void* __restrict__ wq_b, void* __restrict__ wk_b,
                               void* __restrict__ k_b) {
  const int NQ1 = 1048576;   // Wq quads (2048*2048/4)
  const int NQ2 = 1048576;   // Wk quads
  const int NQ3 = 131072;    // k quads
  const int TOT = NQ1 + NQ2 + NQ3;
  for (int i = blockIdx.x * blockDim.x + threadIdx.x; i < TOT;
       i += gridDim.x * blockDim.x) {
    const float4* src; bf16x4* dst; int j;
    if (i < NQ1)           { src = (const float4*)Wq;  dst = (bf16x4*)wq_b; j = i; }
    else if (i < NQ1+NQ2)  { src = (const float4*)Wk;  dst = (bf16x4*)wk_b; j = i - NQ1; }
    else                   { src = (const float4*)kin; dst = (bf16x4*)k_b;  j = i - NQ1 - NQ2; }
    float4 v = src[j];
    bf16x4 o;
    o[0] = (__bf16)v.x; o[1] = (__bf16)v.y; o[2] = (__bf16)v.z; o[3] = (__bf16)v.w;
    dst[j] = o;
  }
}

// ---------------- kl kernel: kl_t[o][c] = bf16(k . Wk^T + bk) ----------------
__global__ __launch_bounds__(256)
void kl_kernel(const void* __restrict__ k_b, const void* __restrict__ wk_b,
               const float* __restrict__ bk, void* __restrict__ kl_t_v) {
  __shared__ char smem[32768];  // 2 bufs x (A 8K + B 8K)
  const __bf16* kb   = (const __bf16*)k_b;
  const __bf16* wkb  = (const __bf16*)wk_b;
  __bf16* kl_t = (__bf16*)kl_t_v;
  const int t = threadIdx.x, w = t >> 6, l = t & 63;
  const int ntile = blockIdx.x, mtile = blockIdx.y;
  const int wr = w >> 1, wc = w & 1;
  f32x4 acc[2][2] = {};

  auto stage = [&](int buf, int kt) {
    const int row = t >> 3;
    const int col = (((t & 7) ^ (row & 7)) << 3);
#pragma unroll
    for (int i = 0; i < 2; ++i) {
      const __bf16* ga = kb + (int64_t)(mtile*64 + i*32 + row) * 2048 + kt*64 + col;
      gload_lds16(ga, smem + buf*16384 + (i*256 + w*64)*16);
      const __bf16* gb = wkb + (int64_t)(ntile*64 + i*32 + row) * 2048 + kt*64 + col;
      gload_lds16(gb, smem + buf*16384 + 8192 + (i*256 + w*64)*16);
    }
  };

  stage(0, 0);
  __syncthreads();
  int cur = 0;
  for (int kt = 0; kt < 32; ++kt) {
    if (kt + 1 < 32) stage(cur ^ 1, kt + 1);
    const char* bA = smem + cur*16384;
    const char* bB = smem + cur*16384 + 8192;
#pragma unroll
    for (int kq = 0; kq < 2; ++kq) {
      bf16x8 a[2], b[2];
      const int g = kq*4 + (l >> 4);
#pragma unroll
      for (int mi = 0; mi < 2; ++mi) {
        const int r = wr*32 + mi*16 + (l & 15);
        a[mi] = *(const bf16x8*)(bA + r*128 + ((g ^ (r & 7)) << 4));
      }
#pragma unroll
      for (int ni = 0; ni < 2; ++ni) {
        const int r = wc*32 + ni*16 + (l & 15);
        b[ni] = *(const bf16x8*)(bB + r*128 + ((g ^ (r & 7)) << 4));
      }
#pragma unroll
      for (int mi = 0; mi < 2; ++mi)
#pragma unroll
        for (int ni = 0; ni < 2; ++ni)
          acc[mi][ni] = __builtin_amdgcn_mfma_f32_16x16x32_bf16(a[mi], b[ni], acc[mi][ni], 0, 0, 0);
    }
    __syncthreads();
    cur ^= 1;
  }

#pragma unroll
  for (int ni = 0; ni < 2; ++ni) {
    const int o = ntile*64 + wc*32 + ni*16 + (l & 15);
    const float bko = bk[o];
#pragma unroll
    for (int mi = 0; mi < 2; ++mi) {
      const int c0 = mtile*64 + wr*32 + mi*16 + (l >> 4)*4;
      bf16x4 v;
      v[0] = (__bf16)(acc[mi][ni][0] + bko);
      v[1] = (__bf16)(acc[mi][ni][1] + bko);
      v[2] = (__bf16)(acc[mi][ni][2] + bko);
      v[3] = (__bf16)(acc[mi][ni][3] + bko);
      *(bf16x4*)(kl_t + (int64_t)o*256 + c0) = v;
    }
  }
}

// ---------------- main fused kernel: BK=32, A reg-staged from f32 q ---------
// Per K-tile kt: issue B(kt+1) gload_lds + A(kt+1) f32 global loads (16 VGPR),
// compute (12 ds_read_b128 + 32 MFMA, compiler-scheduled), then vmcnt(0) ->
// cast+ds_write A(kt+1), lgkmcnt(0), one s_barrier. A-load latency (~HBM 900
// cyc first-touch, L3 after) hides under the ~1500-cyc compute window.
__global__ __launch_bounds__(512, 2)
void main_kernel(const float* __restrict__ qf, const void* __restrict__ wq_b,
                 const float* __restrict__ bq, const void* __restrict__ kl_t_v,
                 float* __restrict__ out) {
  __shared__ char smem[65536];  // A: 2x16K [0,32K); B: 2x16K [32K,64K)
  const __bf16* wqb  = (const __bf16*)wq_b;
  const __bf16* kl_t = (const __bf16*)kl_t_v;
  const int t = threadIdx.x, w = t >> 6, l = t & 63;
  // XCD-aware swizzle: lid%8 == XCD hosts b with b%8 == xcd; the 8 otiles of
  // each b are consecutive slots on that XCD -> q-panel HBM-fetched once.
  const int lid = blockIdx.x + 8 * blockIdx.y;   // bijective remap, grid=2048
  const int xcd = lid & 7, slot = lid >> 3;
  const int otile = slot & 7;
  const int b = ((slot >> 3) << 3) | xcd;
  const int wr = w >> 2, wc = w & 3;
  const int crow = t >> 1, chalf = t & 1;  // A staging: thread owns 64B of row crow
  f32x4 acc[8][4] = {};

  // A: load 16 f32 (64B, line-aligned slice) of q[crow, b, kt*32 + chalf*16 ..]
  auto loadA = [&](int kt, float4* v) {
    const float4* src =
        (const float4*)(qf + (int64_t)(crow*256 + b) * 2048 + kt*32) + chalf*4;
#pragma unroll
    for (int j = 0; j < 4; ++j) v[j] = src[j];
  };
  // cast to bf16 and write 2x16B to swizzled slots of row crow in A buf
  auto writeA = [&](int buf, const float4* v) {
    bf16x8 lo, hi;
    lo[0]=(__bf16)v[0].x; lo[1]=(__bf16)v[0].y; lo[2]=(__bf16)v[0].z; lo[3]=(__bf16)v[0].w;
    lo[4]=(__bf16)v[1].x; lo[5]=(__bf16)v[1].y; lo[6]=(__bf16)v[1].z; lo[7]=(__bf16)v[1].w;
    hi[0]=(__bf16)v[2].x; hi[1]=(__bf16)v[2].y; hi[2]=(__bf16)v[2].z; hi[3]=(__bf16)v[2].w;
    hi[4]=(__bf16)v[3].x; hi[5]=(__bf16)v[3].y; hi[6]=(__bf16)v[3].z; hi[7]=(__bf16)v[3].w;
    const int s = crow & 3;
    char* base = smem + buf*16384 + crow*64;
    *(bf16x8*)(base + (((2*chalf    ) ^ s) << 4)) = lo;
    *(bf16x8*)(base + (((2*chalf + 1) ^ s) << 4)) = hi;
  };
  // B: stage 16KB bf16 tile of Wq via global_load_lds (pre-swizzled source)
  auto stageB = [&](int buf, int kt) {
#pragma unroll
    for (int i = 0; i < 2; ++i) {
      const int r = i*128 + (t >> 2);
      const int sg = (t & 3) ^ (r & 3);
      const __bf16* gb = wqb + (int64_t)(otile*256 + r) * 2048 + kt*32 + sg*8;
      gload_lds16(gb, smem + 32768 + buf*16384 + i*8192 + t*16);
    }
  };
  // 12 ds_read_b128 + 32 MFMA; rows are 64B, XOR-swizzled over 4 16B groups
  auto compute = [&](int abuf, int bbuf) {
    const char* bA_ = smem + abuf*16384;
    const char* bB_ = smem + 32768 + bbuf*16384;
    const int g_ = l >> 4;
    bf16x8 af[8], bfr[4];
#pragma unroll
    for (int m2 = 0; m2 < 8; ++m2) {
      const int r_ = wr*128 + m2*16 + (l & 15);
      af[m2] = *(const bf16x8*)(bA_ + r_*64 + ((g_ ^ (r_ & 3)) << 4));
    }
#pragma unroll
    for (int n2 = 0; n2 < 4; ++n2) {
      const int r_ = wc*64 + n2*16 + (l & 15);
      bfr[n2] = *(const bf16x8*)(bB_ + r_*64 + ((g_ ^ (r_ & 3)) << 4));
    }
#pragma unroll
    for (int m2 = 0; m2 < 8; ++m2)
#pragma unroll
      for (int n2 = 0; n2 < 4; ++n2)
        acc[m2][n2] = __builtin_amdgcn_mfma_f32_16x16x32_bf16(
            af[m2], bfr[n2], acc[m2][n2], 0, 0, 0);
  };

  float4 av[4];
  // prologue: tile 0 into buf 0
  loadA(0, av);
  stageB(0, 0);
  asm volatile("s_waitcnt vmcnt(0)" ::: "memory");
  writeA(0, av);
  asm volatile("s_waitcnt lgkmcnt(0)" ::: "memory");
  __builtin_amdgcn_s_barrier();

  for (int kt = 0; kt < 64; ++kt) {
    const int cur = kt & 1, nxt = cur ^ 1;
    if (kt < 63) {
      stageB(nxt, kt + 1);   // async into B buf nxt (free since end of kt-1)
      loadA(kt + 1, av);     // f32 -> regs; latency hidden under compute
    }
    compute(cur, cur);
    if (kt < 63) {
      asm volatile("s_waitcnt vmcnt(0)" ::: "memory");  // A regs + B LDS ready
      writeA(nxt, av);
    }
    asm volatile("s_waitcnt lgkmcnt(0)" ::: "memory");  // ds_writes visible
    __builtin_amdgcn_s_barrier();
  }

  // ---- epilogue ----
  // C/D frag layout: row(c) = wr*128 + mi*16 + (l>>4)*4 + reg, col(o) = wc*64 + ni*16 + (l&15)
  float psum[4] = {0.f, 0.f, 0.f, 0.f};
#pragma unroll
  for (int ni = 0; ni < 4; ++ni) {
    const int o = otile*256 + wc*64 + ni*16 + (l & 15);
    const float bqo = bq[o];
    const __bf16* klc = kl_t + (int64_t)o * 256 + wr*128 + (l >> 4)*4;
#pragma unroll
    for (int mi = 0; mi < 8; ++mi) {
      bf16x4 kv = *(const bf16x4*)(klc + mi*16);
      psum[ni] += (acc[mi][ni][0] + bqo) * (float)kv[0]
                + (acc[mi][ni][1] + bqo) * (float)kv[1]
                + (acc[mi][ni][2] + bqo) * (float)kv[2]
                + (acc[mi][ni][3] + bqo) * (float)kv[3];
    }
  }
#pragma unroll
  for (int ni = 0; ni < 4; ++ni) {  // reduce over the 4 row-groups (l>>4)
    psum[ni] += __shfl_xor(psum[ni], 16);
    psum[ni] += __shfl_xor(psum[ni], 32);
  }
  float* red = (float*)smem;  // [2][256] f32 in A buf0 (last tile read buf1)
  if (l < 16) {
#pragma unroll
    for (int ni = 0; ni < 4; ++ni)
      red[wr*256 + wc*64 + ni*16 + l] = psum[ni];
  }
  __syncthreads();
  if (t < 256) {
    const float s = 0.0625f * (red[t] + red[256 + t]);  // fact * S[b, otile*256+t]
    float m = s;
    m = fmaxf(m, __shfl_xor(m, 1));
    m = fmaxf(m, __shfl_xor(m, 2));
    m = fmaxf(m, __shfl_xor(m, 4));
    const float e = __expf(s - m);
    float sum = e;
    sum += __shfl_xor(sum, 1);
    sum += __shfl_xor(sum, 2);
    sum += __shfl_xor(sum, 4);
    out[(int64_t)b*2048 + otile*256 + t] = e / sum;
  }
}

extern "C" void kernel_launch(void* const* d_in, const int* in_sizes, int n_in,
                              void* d_out, int out_size, void* d_ws, size_t ws_size,
                              hipStream_t stream) {
  (void)in_sizes; (void)n_in; (void)out_size; (void)ws_size;
  const float* q  = (const float*)d_in[0];
  const float* k  = (const float*)d_in[1];
  const float* Wq = (const float*)d_in[2];
  const float* bq = (const float*)d_in[3];
  const float* Wk = (const float*)d_in[4];
  const float* bk = (const float*)d_in[5];
  float* out = (float*)d_out;
  char* ws = (char*)d_ws;
  void* wq_b = ws;                          // 8 MiB    Wq bf16
  void* wk_b = ws + 8388608;                // 8 MiB    Wk bf16
  void* k_b  = ws + 16777216;               // 1 MiB    k bf16
  void* kl_t = ws + 17825792;               // 1 MiB    kl_t bf16 [2048 o][256 c]

  convert_kernel<<<1024, 256, 0, stream>>>(Wq, Wk, k, wq_b, wk_b, k_b);
  kl_kernel<<<dim3(32, 4), 256, 0, stream>>>(k_b, wk_b, bk, kl_t);
  main_kernel<<<dim3(8, 256), 512, 0, stream>>>(q, wq_b, bq, kl_t, out);
}

// Round 5
// 1031.834 us; speedup vs baseline: 1.4413x; 1.4413x over previous
//
#include <hip/hip_runtime.h>
#include <stdint.h>

// out[b, q, n] = softmax_n( fact * S[b, q*8+n] ),  S[b,o] = sum_c ql[c,b,o]*kl[c,o]
//   ql[c,b,o] = sum_h q[c,b,h]*Wq[o,h] + bq[o]
//   kl[c,o]   = sum_d k[c,d]*Wk[o,d] + bk[o]
// A=B=256, H=QD=2048, n=8, fact = 1/16.
//
// R5 = R3 structure (BK=64, 128B-row XOR-swizzled LDS = 0 bank conflicts,
// 1 barrier/tile, counted vmcnt, XCD swizzle) + inline A-staging from f32 q
// (kills the ~130us q-convert pre-pass): per tile, 2 half-batches of 16 f32
// regs -> bf16 -> ds_write_b128 into the next A buf, hidden under compute.
// + wave stagger: waves 0-3 do k-half0 first, 4-7 do k-half1 first, so the
// two waves per SIMD are in opposite LDS-read/MFMA phases (anti-convoy).

typedef __attribute__((ext_vector_type(8))) __bf16 bf16x8;
typedef __attribute__((ext_vector_type(4))) __bf16 bf16x4;
typedef __attribute__((ext_vector_type(4))) float f32x4;

__device__ __forceinline__ void gload_lds16(const void* g, void* l) {
  __builtin_amdgcn_global_load_lds(
      (const __attribute__((address_space(1))) uint32_t*)g,
      (__attribute__((address_space(3))) uint32_t*)l, 16, 0, 0);
}

// ---------------- convert: Wq, Wk, k (f32) -> bf16 (q handled in main) -----
__global__ void convert_kernel(const float* __restrict__ Wq,
                               const float* __restrict__ Wk,
                               const float* __restrict__ kin,
                               void* __restrict__ wq_b, void* __restrict__ wk_b,
                               void* __restrict__ k_b) {
  const int NQ1 = 1048576;   // Wq quads (2048*2048/4)
  const int NQ2 = 1048576;   // Wk quads
  const int NQ3 = 131072;    // k quads
  const int TOT = NQ1 + NQ2 + NQ3;
  for (int i = blockIdx.x * blockDim.x + threadIdx.x; i < TOT;
       i += gridDim.x * blockDim.x) {
    const float4* src; bf16x4* dst; int j;
    if (i < NQ1)           { src = (const float4*)Wq;  dst = (bf16x4*)wq_b; j = i; }
    else if (i < NQ1+NQ2)  { src = (const float4*)Wk;  dst = (bf16x4*)wk_b; j = i - NQ1; }
    else                   { src = (const float4*)kin; dst = (bf16x4*)k_b;  j = i - NQ1 - NQ2; }
    float4 v = src[j];
    bf16x4 o;
    o[0] = (__bf16)v.x; o[1] = (__bf16)v.y; o[2] = (__bf16)v.z; o[3] = (__bf16)v.w;
    dst[j] = o;
  }
}

// ---------------- kl kernel: kl_t[o][c] = bf16(k . Wk^T + bk) ----------------
__global__ __launch_bounds__(256)
void kl_kernel(const void* __restrict__ k_b, const void* __restrict__ wk_b,
               const float* __restrict__ bk, void* __restrict__ kl_t_v) {
  __shared__ char smem[32768];  // 2 bufs x (A 8K + B 8K)
  const __bf16* kb   = (const __bf16*)k_b;
  const __bf16* wkb  = (const __bf16*)wk_b;
  __bf16* kl_t = (__bf16*)kl_t_v;
  const int t = threadIdx.x, w = t >> 6, l = t & 63;
  const int ntile = blockIdx.x, mtile = blockIdx.y;
  const int wr = w >> 1, wc = w & 1;
  f32x4 acc[2][2] = {};

  auto stage = [&](int buf, int kt) {
    const int row = t >> 3;
    const int col = (((t & 7) ^ (row & 7)) << 3);
#pragma unroll
    for (int i = 0; i < 2; ++i) {
      const __bf16* ga = kb + (int64_t)(mtile*64 + i*32 + row) * 2048 + kt*64 + col;
      gload_lds16(ga, smem + buf*16384 + (i*256 + w*64)*16);
      const __bf16* gb = wkb + (int64_t)(ntile*64 + i*32 + row) * 2048 + kt*64 + col;
      gload_lds16(gb, smem + buf*16384 + 8192 + (i*256 + w*64)*16);
    }
  };

  stage(0, 0);
  __syncthreads();
  int cur = 0;
  for (int kt = 0; kt < 32; ++kt) {
    if (kt + 1 < 32) stage(cur ^ 1, kt + 1);
    const char* bA = smem + cur*16384;
    const char* bB = smem + cur*16384 + 8192;
#pragma unroll
    for (int kq = 0; kq < 2; ++kq) {
      bf16x8 a[2], b[2];
      const int g = kq*4 + (l >> 4);
#pragma unroll
      for (int mi = 0; mi < 2; ++mi) {
        const int r = wr*32 + mi*16 + (l & 15);
        a[mi] = *(const bf16x8*)(bA + r*128 + ((g ^ (r & 7)) << 4));
      }
#pragma unroll
      for (int ni = 0; ni < 2; ++ni) {
        const int r = wc*32 + ni*16 + (l & 15);
        b[ni] = *(const bf16x8*)(bB + r*128 + ((g ^ (r & 7)) << 4));
      }
#pragma unroll
      for (int mi = 0; mi < 2; ++mi)
#pragma unroll
        for (int ni = 0; ni < 2; ++ni)
          acc[mi][ni] = __builtin_amdgcn_mfma_f32_16x16x32_bf16(a[mi], b[ni], acc[mi][ni], 0, 0, 0);
    }
    __syncthreads();
    cur ^= 1;
  }

#pragma unroll
  for (int ni = 0; ni < 2; ++ni) {
    const int o = ntile*64 + wc*32 + ni*16 + (l & 15);
    const float bko = bk[o];
#pragma unroll
    for (int mi = 0; mi < 2; ++mi) {
      const int c0 = mtile*64 + wr*32 + mi*16 + (l >> 4)*4;
      bf16x4 v;
      v[0] = (__bf16)(acc[mi][ni][0] + bko);
      v[1] = (__bf16)(acc[mi][ni][1] + bko);
      v[2] = (__bf16)(acc[mi][ni][2] + bko);
      v[3] = (__bf16)(acc[mi][ni][3] + bko);
      *(bf16x4*)(kl_t + (int64_t)o*256 + c0) = v;
    }
  }
}

// ---------------- main fused kernel --------------------------------------
// Per K-tile kt (BK=64): stageB(kt+1) via gload_lds; computeH(half hs);
// vmcnt(4) -> A(kt+1) half0 f32 arrived -> cvt+ds_write; issue half1 loads;
// computeH(hs^1); vmcnt(0) -> half1 + B done -> cvt+ds_write; issue
// A(kt+2) half0; lgkmcnt(0); s_barrier. LDS 128K: A 2x32K, B 2x32K.
__global__ __launch_bounds__(512, 2)
void main_kernel(const float* __restrict__ qf, const void* __restrict__ wq_b,
                 const float* __restrict__ bq, const void* __restrict__ kl_t_v,
                 float* __restrict__ out) {
  __shared__ char smem[131072];  // A: 2x32K [0,64K); B: 2x32K [64K,128K)
  const __bf16* wqb  = (const __bf16*)wq_b;
  const __bf16* kl_t = (const __bf16*)kl_t_v;
  const int t = threadIdx.x, w = t >> 6, l = t & 63;
  // XCD-aware swizzle: lid%8 == XCD hosts b with b%8 == xcd; the 8 otiles of
  // each b are consecutive slots on that XCD -> q-panel HBM-fetched once.
  const int lid = blockIdx.x + 8 * blockIdx.y;   // bijective remap, grid=2048
  const int xcd = lid & 7, slot = lid >> 3;
  const int otile = slot & 7;
  const int b = ((slot >> 3) << 3) | xcd;
  const int wr = w >> 2, wc = w & 3;
  f32x4 acc[8][4] = {};

  // ---- A staging: thread owns k-elems [chalf*32, +32) of row crow ----
  const int crow = t >> 1, chalf = t & 1;
  const float* aSrc = qf + (int64_t)(crow*256 + b) * 2048 + chalf*32;
  float4 Q[4];  // 16 f32 = one half-batch (k-elems hh*16 + [0,16))
  auto loadAH = [&](int kt, int hh) {
    const float4* s = (const float4*)(aSrc + kt*64 + hh*16);
    Q[0] = s[0]; Q[1] = s[1]; Q[2] = s[2]; Q[3] = s[3];
  };
  auto writeAH = [&](int buf, int hh) {
    bf16x8 lo, hi;
    lo[0]=(__bf16)Q[0].x; lo[1]=(__bf16)Q[0].y; lo[2]=(__bf16)Q[0].z; lo[3]=(__bf16)Q[0].w;
    lo[4]=(__bf16)Q[1].x; lo[5]=(__bf16)Q[1].y; lo[6]=(__bf16)Q[1].z; lo[7]=(__bf16)Q[1].w;
    hi[0]=(__bf16)Q[2].x; hi[1]=(__bf16)Q[2].y; hi[2]=(__bf16)Q[2].z; hi[3]=(__bf16)Q[2].w;
    hi[4]=(__bf16)Q[3].x; hi[5]=(__bf16)Q[3].y; hi[6]=(__bf16)Q[3].z; hi[7]=(__bf16)Q[3].w;
    const int g0 = chalf*4 + hh*2, s = crow & 7;
    char* base = smem + buf*32768 + crow*128;
    *(bf16x8*)(base + (((g0    ) ^ s) << 4)) = lo;
    *(bf16x8*)(base + (((g0 + 1) ^ s) << 4)) = hi;
  };
  // ---- B staging: 32KB bf16 tile of Wq via gload_lds, pre-swizzled src ----
  auto stageB = [&](int buf, int kt) {
#pragma unroll
    for (int i = 0; i < 2; ++i)
#pragma unroll
      for (int half = 0; half < 2; ++half) {
        const int row64 = t >> 3;
        const int r = i*128 + half*32 + (row64 & 31) + ((row64 >> 5) << 6);
        const int sg = (t & 7) ^ (r & 7);
        const __bf16* gb = wqb + (int64_t)(otile*256 + r) * 2048 + kt*64 + sg*8;
        gload_lds16(gb, smem + 65536 + buf*32768 + r*128 + (t & 7)*16);
      }
  };
  // ---- one k-half of the tile: 12 ds_read_b128 + 32 MFMA ----
  auto computeH = [&](int abuf, int bbuf, int h) {
    const char* bA_ = smem + abuf*32768;
    const char* bB_ = smem + 65536 + bbuf*32768;
    const int g_ = h*4 + (l >> 4);
    bf16x8 af[8], bfr[4];
#pragma unroll
    for (int m2 = 0; m2 < 8; ++m2) {
      const int r_ = wr*128 + m2*16 + (l & 15);
      af[m2] = *(const bf16x8*)(bA_ + r_*128 + ((g_ ^ (r_ & 7)) << 4));
    }
#pragma unroll
    for (int n2 = 0; n2 < 4; ++n2) {
      const int r_ = wc*64 + n2*16 + (l & 15);
      bfr[n2] = *(const bf16x8*)(bB_ + r_*128 + ((g_ ^ (r_ & 7)) << 4));
    }
#pragma unroll
    for (int m2 = 0; m2 < 8; ++m2)
#pragma unroll
      for (int n2 = 0; n2 < 4; ++n2)
        acc[m2][n2] = __builtin_amdgcn_mfma_f32_16x16x32_bf16(
            af[m2], bfr[n2], acc[m2][n2], 0, 0, 0);
  };

  // prologue: tile0 A+B into buf0; leave A(1) half0 in flight
  loadAH(0, 0);
  stageB(0, 0);                                        // queue [A*4, B*4]
  asm volatile("s_waitcnt vmcnt(4)" ::: "memory");     // A half0 arrived
  writeAH(0, 0);
  loadAH(0, 1);                                        // queue [B*4, A*4]
  asm volatile("s_waitcnt vmcnt(0)" ::: "memory");
  writeAH(0, 1);
  loadAH(1, 0);                                        // queue [A(1)h0*4]
  asm volatile("s_waitcnt lgkmcnt(0)" ::: "memory");
  __builtin_amdgcn_s_barrier();

  const int hs = (w >> 2) & 1;  // SIMD-mates (w, w+4) start opposite halves
  for (int kt = 0; kt < 32; ++kt) {
    const int cur = kt & 1, nxt = cur ^ 1;
    if (kt < 31) stageB(nxt, kt + 1);                  // [Ah0*4, B*4]
    computeH(cur, cur, hs);
    if (kt < 31) {
      asm volatile("s_waitcnt vmcnt(4)" ::: "memory"); // A(kt+1)h0 arrived
      writeAH(nxt, 0);
      loadAH(kt + 1, 1);                               // [B*4, Ah1*4]
    }
    computeH(cur, cur, hs ^ 1);
    if (kt < 31) {
      asm volatile("s_waitcnt vmcnt(0)" ::: "memory"); // B + A(kt+1)h1 done
      writeAH(nxt, 1);
      if (kt < 30) loadAH(kt + 2, 0);                  // [A(kt+2)h0*4]
    }
    asm volatile("s_waitcnt lgkmcnt(0)" ::: "memory"); // ds_writes visible
    __builtin_amdgcn_s_barrier();
  }

  // ---- epilogue ----
  // C/D frag layout: row(c) = wr*128 + mi*16 + (l>>4)*4 + reg, col(o) = wc*64 + ni*16 + (l&15)
  float psum[4] = {0.f, 0.f, 0.f, 0.f};
#pragma unroll
  for (int ni = 0; ni < 4; ++ni) {
    const int o = otile*256 + wc*64 + ni*16 + (l & 15);
    const float bqo = bq[o];
    const __bf16* klc = kl_t + (int64_t)o * 256 + wr*128 + (l >> 4)*4;
#pragma unroll
    for (int mi = 0; mi < 8; ++mi) {
      bf16x4 kv = *(const bf16x4*)(klc + mi*16);
      psum[ni] += (acc[mi][ni][0] + bqo) * (float)kv[0]
                + (acc[mi][ni][1] + bqo) * (float)kv[1]
                + (acc[mi][ni][2] + bqo) * (float)kv[2]
                + (acc[mi][ni][3] + bqo) * (float)kv[3];
    }
  }
#pragma unroll
  for (int ni = 0; ni < 4; ++ni) {  // reduce over the 4 row-groups (l>>4)
    psum[ni] += __shfl_xor(psum[ni], 16);
    psum[ni] += __shfl_xor(psum[ni], 32);
  }
  float* red = (float*)smem;  // A buf0 region; dead after final barrier
  if (l < 16) {
#pragma unroll
    for (int ni = 0; ni < 4; ++ni)
      red[wr*256 + wc*64 + ni*16 + l] = psum[ni];
  }
  __syncthreads();
  if (t < 256) {
    const float s = 0.0625f * (red[t] + red[256 + t]);  // fact * S[b, otile*256+t]
    float m = s;
    m = fmaxf(m, __shfl_xor(m, 1));
    m = fmaxf(m, __shfl_xor(m, 2));
    m = fmaxf(m, __shfl_xor(m, 4));
    const float e = __expf(s - m);
    float sum = e;
    sum += __shfl_xor(sum, 1);
    sum += __shfl_xor(sum, 2);
    sum += __shfl_xor(sum, 4);
    out[(int64_t)b*2048 + otile*256 + t] = e / sum;
  }
}

extern "C" void kernel_launch(void* const* d_in, const int* in_sizes, int n_in,
                              void* d_out, int out_size, void* d_ws, size_t ws_size,
                              hipStream_t stream) {
  (void)in_sizes; (void)n_in; (void)out_size; (void)ws_size;
  const float* q  = (const float*)d_in[0];
  const float* k  = (const float*)d_in[1];
  const float* Wq = (const float*)d_in[2];
  const float* bq = (const float*)d_in[3];
  const float* Wk = (const float*)d_in[4];
  const float* bk = (const float*)d_in[5];
  float* out = (float*)d_out;
  char* ws = (char*)d_ws;
  void* wq_b = ws;                          // 8 MiB    Wq bf16
  void* wk_b = ws + 8388608;                // 8 MiB    Wk bf16
  void* k_b  = ws + 16777216;               // 1 MiB    k bf16
  void* kl_t = ws + 17825792;               // 1 MiB    kl_t bf16 [2048 o][256 c]

  convert_kernel<<<1024, 256, 0, stream>>>(Wq, Wk, k, wq_b, wk_b, k_b);
  kl_kernel<<<dim3(32, 4), 256, 0, stream>>>(k_b, wk_b, bk, kl_t);
  main_kernel<<<dim3(8, 256), 512, 0, stream>>>(q, wq_b, bq, kl_t, out);
}

// Round 6
// 656.514 us; speedup vs baseline: 2.2652x; 1.5717x over previous
//
#include <hip/hip_runtime.h>
#include <stdint.h>

// out[b, q, n] = softmax_n( fact * S[b, q*8+n] ),  S[b,o] = sum_c ql[c,b,o]*kl[c,o]
//   ql[c,b,o] = sum_h q[c,b,h]*Wq[o,h] + bq[o]
//   kl[c,o]   = sum_d k[c,d]*Wk[o,d] + bk[o]
// A=B=256, H=QD=2048, n=8, fact = 1/16.
//
// R6 = R3 (best main: 523us, 0 bank conflicts, FETCH 426MB, XCD swizzle,
// BK=64, A 3-buf / B 2-buf, 1 barrier/tile, counted vmcnt) with the compute
// half restructured to break the measured LDS->MFMA serialization (R3 wall
// 4903 cyc/tile == 2304 LDS + 2484 MFMA, exactly serial): bfr[0..3]+af[0]
// read first, then 1-ahead {read af[m2+1]; 4 MFMA on af[m2]} chain, pinned
// with sched_group_barrier (T19) so both pipes overlap -> target ~3000 cyc.

typedef __attribute__((ext_vector_type(8))) __bf16 bf16x8;
typedef __attribute__((ext_vector_type(4))) __bf16 bf16x4;
typedef __attribute__((ext_vector_type(4))) float f32x4;

__device__ __forceinline__ void gload_lds16(const void* g, void* l) {
  __builtin_amdgcn_global_load_lds(
      (const __attribute__((address_space(1))) uint32_t*)g,
      (__attribute__((address_space(3))) uint32_t*)l, 16, 0, 0);
}

// ---------------- convert: q (f32, transpose to [b][c][h]), Wq, Wk, k -> bf16
__global__ void convert_kernel(const float* __restrict__ qin,
                               const float* __restrict__ Wq,
                               const float* __restrict__ Wk,
                               const float* __restrict__ kin,
                               void* __restrict__ q_t,
                               void* __restrict__ wq_b, void* __restrict__ wk_b,
                               void* __restrict__ k_b) {
  const int NQ0 = 33554432;  // q float4 quads (256*256*2048/4); 512 quads/row
  const int NQ1 = 1048576;   // Wq quads
  const int NQ2 = 1048576;   // Wk quads
  const int NQ3 = 131072;    // k quads
  const int TOT = NQ0 + NQ1 + NQ2 + NQ3;
  for (int i = blockIdx.x * blockDim.x + threadIdx.x; i < TOT;
       i += gridDim.x * blockDim.x) {
    if (i < NQ0) {
      // src quad i = ((c*256)+b)*512 + jq  ->  dst quad = ((b*256)+c)*512 + jq
      float4 v = ((const float4*)qin)[i];
      const int jq = i & 511;
      const int b  = (i >> 9) & 255;
      const int c  = i >> 17;
      bf16x4 o;
      o[0] = (__bf16)v.x; o[1] = (__bf16)v.y; o[2] = (__bf16)v.z; o[3] = (__bf16)v.w;
      ((bf16x4*)q_t)[(int64_t)(((b << 8) + c) << 9) + jq] = o;
    } else {
      const float4* src; bf16x4* dst; int j;
      if (i < NQ0+NQ1)              { src = (const float4*)Wq;  dst = (bf16x4*)wq_b; j = i - NQ0; }
      else if (i < NQ0+NQ1+NQ2)     { src = (const float4*)Wk;  dst = (bf16x4*)wk_b; j = i - NQ0 - NQ1; }
      else                          { src = (const float4*)kin; dst = (bf16x4*)k_b;  j = i - NQ0 - NQ1 - NQ2; }
      float4 v = src[j];
      bf16x4 o;
      o[0] = (__bf16)v.x; o[1] = (__bf16)v.y; o[2] = (__bf16)v.z; o[3] = (__bf16)v.w;
      dst[j] = o;
    }
  }
}

// ---------------- kl kernel: kl_t[o][c] = bf16(k . Wk^T + bk) ----------------
__global__ __launch_bounds__(256)
void kl_kernel(const void* __restrict__ k_b, const void* __restrict__ wk_b,
               const float* __restrict__ bk, void* __restrict__ kl_t_v) {
  __shared__ char smem[32768];  // 2 bufs x (A 8K + B 8K)
  const __bf16* kb   = (const __bf16*)k_b;
  const __bf16* wkb  = (const __bf16*)wk_b;
  __bf16* kl_t = (__bf16*)kl_t_v;
  const int t = threadIdx.x, w = t >> 6, l = t & 63;
  const int ntile = blockIdx.x, mtile = blockIdx.y;
  const int wr = w >> 1, wc = w & 1;
  f32x4 acc[2][2] = {};

  auto stage = [&](int buf, int kt) {
    const int row = t >> 3;
    const int col = (((t & 7) ^ (row & 7)) << 3);
#pragma unroll
    for (int i = 0; i < 2; ++i) {
      const __bf16* ga = kb + (int64_t)(mtile*64 + i*32 + row) * 2048 + kt*64 + col;
      gload_lds16(ga, smem + buf*16384 + (i*256 + w*64)*16);
      const __bf16* gb = wkb + (int64_t)(ntile*64 + i*32 + row) * 2048 + kt*64 + col;
      gload_lds16(gb, smem + buf*16384 + 8192 + (i*256 + w*64)*16);
    }
  };

  stage(0, 0);
  __syncthreads();
  int cur = 0;
  for (int kt = 0; kt < 32; ++kt) {
    if (kt + 1 < 32) stage(cur ^ 1, kt + 1);
    const char* bA = smem + cur*16384;
    const char* bB = smem + cur*16384 + 8192;
#pragma unroll
    for (int kq = 0; kq < 2; ++kq) {
      bf16x8 a[2], b[2];
      const int g = kq*4 + (l >> 4);
#pragma unroll
      for (int mi = 0; mi < 2; ++mi) {
        const int r = wr*32 + mi*16 + (l & 15);
        a[mi] = *(const bf16x8*)(bA + r*128 + ((g ^ (r & 7)) << 4));
      }
#pragma unroll
      for (int ni = 0; ni < 2; ++ni) {
        const int r = wc*32 + ni*16 + (l & 15);
        b[ni] = *(const bf16x8*)(bB + r*128 + ((g ^ (r & 7)) << 4));
      }
#pragma unroll
      for (int mi = 0; mi < 2; ++mi)
#pragma unroll
        for (int ni = 0; ni < 2; ++ni)
          acc[mi][ni] = __builtin_amdgcn_mfma_f32_16x16x32_bf16(a[mi], b[ni], acc[mi][ni], 0, 0, 0);
    }
    __syncthreads();
    cur ^= 1;
  }

#pragma unroll
  for (int ni = 0; ni < 2; ++ni) {
    const int o = ntile*64 + wc*32 + ni*16 + (l & 15);
    const float bko = bk[o];
#pragma unroll
    for (int mi = 0; mi < 2; ++mi) {
      const int c0 = mtile*64 + wr*32 + mi*16 + (l >> 4)*4;
      bf16x4 v;
      v[0] = (__bf16)(acc[mi][ni][0] + bko);
      v[1] = (__bf16)(acc[mi][ni][1] + bko);
      v[2] = (__bf16)(acc[mi][ni][2] + bko);
      v[3] = (__bf16)(acc[mi][ni][3] + bko);
      *(bf16x4*)(kl_t + (int64_t)o*256 + c0) = v;
    }
  }
}

// ---------------- main fused kernel: 1 barrier per K-tile, pipelined halves -
__global__ __launch_bounds__(512, 2)
void main_kernel(const void* __restrict__ q_tv, const void* __restrict__ wq_b,
                 const float* __restrict__ bq, const void* __restrict__ kl_t_v,
                 float* __restrict__ out) {
  __shared__ char smem[163840];  // A: 3x32K [0,96K); B: 2x32K [96K,160K)
  const __bf16* qt   = (const __bf16*)q_tv;   // [b][c][h] bf16
  const __bf16* wqb  = (const __bf16*)wq_b;
  const __bf16* kl_t = (const __bf16*)kl_t_v;
  const int t = threadIdx.x, w = t >> 6, l = t & 63;
  // XCD-aware swizzle: lid%8 == XCD hosts b with b%8 == xcd; the 8 otiles of
  // each b are consecutive slots on that XCD -> q-panel L2-reused 8x.
  const int lid = blockIdx.x + 8 * blockIdx.y;   // bijective remap, grid=2048
  const int xcd = lid & 7, slot = lid >> 3;
  const int otile = slot & 7;
  const int b = ((slot >> 3) << 3) | xcd;
  const int wr = w >> 2, wc = w & 3;
  f32x4 acc[8][4] = {};

  // stage A row-half of tile kt (rows half*64+[0,64) and 128+half*64+[0,64))
  auto stageA = [&](int buf, int kt, int half) {
#pragma unroll
    for (int i = 0; i < 2; ++i) {
      const int r = i*128 + half*64 + (t >> 3);
      const int sg = (t & 7) ^ (r & 7);
      const __bf16* ga = qt + (int64_t)(b*256 + r) * 2048 + kt*64 + sg*8;
      gload_lds16(ga, smem + buf*32768 + r*128 + (t & 7)*16);
    }
  };
  // stage B row-half of tile kt
  auto stageB = [&](int buf, int kt, int half) {
#pragma unroll
    for (int i = 0; i < 2; ++i) {
      const int row64 = t >> 3;
      const int r = i*128 + half*32 + (row64 & 31) + ((row64 >> 5) << 6);
      const int sg = (t & 7) ^ (r & 7);
      const __bf16* gb = wqb + (int64_t)(otile*256 + r) * 2048 + kt*64 + sg*8;
      gload_lds16(gb, smem + 98304 + buf*32768 + r*128 + (t & 7)*16);
    }
  };

  // one k-half: bfr[0..3]+af0 first, then 1-ahead {read af[m2+1]; 4 MFMA}.
  // sched_group_barrier pins the DS_READ/MFMA interleave (T19) so the LDS
  // and matrix pipes overlap instead of the measured serial burst pattern.
  auto computeH = [&](int abuf, int bbuf, int h) {
    const char* bA_ = smem + abuf*32768;
    const char* bB_ = smem + 98304 + bbuf*32768;
    const int g_ = h*4 + (l >> 4);
    bf16x8 bfr[4];
#pragma unroll
    for (int n2 = 0; n2 < 4; ++n2) {
      const int r_ = wc*64 + n2*16 + (l & 15);
      bfr[n2] = *(const bf16x8*)(bB_ + r_*128 + ((g_ ^ (r_ & 7)) << 4));
    }
    auto readA = [&](int m2) {
      const int r_ = wr*128 + m2*16 + (l & 15);
      return *(const bf16x8*)(bA_ + r_*128 + ((g_ ^ (r_ & 7)) << 4));
    };
    bf16x8 afc = readA(0);
    __builtin_amdgcn_sched_group_barrier(0x100, 5, 0);  // 4 bfr + af0
#pragma unroll
    for (int m2 = 0; m2 < 8; ++m2) {
      bf16x8 afn = afc;
      if (m2 < 7) {
        afn = readA(m2 + 1);
        __builtin_amdgcn_sched_group_barrier(0x100, 1, 0);  // next-A read
      }
#pragma unroll
      for (int n2 = 0; n2 < 4; ++n2)
        acc[m2][n2] = __builtin_amdgcn_mfma_f32_16x16x32_bf16(
            afc, bfr[n2], acc[m2][n2], 0, 0, 0);
      __builtin_amdgcn_sched_group_barrier(0x8, 4, 0);      // 4 MFMAs
      afc = afn;
    }
  };

  // prologue: A(0), B(0) full + A(1) full; vmcnt(4) -> tile0 complete,
  // A(1) (4 loads) stays in flight == steady-state entry condition.
  stageA(0, 0, 0); stageA(0, 0, 1);
  stageB(0, 0, 0); stageB(0, 0, 1);
  stageA(1, 1, 0); stageA(1, 1, 1);
  asm volatile("s_waitcnt vmcnt(4)" ::: "memory");
  __builtin_amdgcn_s_barrier();

  int ac = 0;  // A-buf holding tile kt (= kt % 3)
  for (int kt = 0; kt < 32; ++kt) {
    const int as = (ac >= 1) ? ac - 1 : 2;  // (kt+2) % 3
    const int bc = kt & 1, bs = bc ^ 1;
    // issue next-tile stages first (vmem latency hides under compute)
    if (kt < 31) { stageB(bs, kt + 1, 0); stageB(bs, kt + 1, 1); }
    if (kt < 30) { stageA(as, kt + 2, 0); stageA(as, kt + 2, 1); }
    computeH(ac, bc, 0);
    computeH(ac, bc, 1);
    // fence: oldest 8 in flight = A(kt+1)+B(kt+1); keep A(kt+2) in flight
    if (kt < 30)      { asm volatile("s_waitcnt vmcnt(4)" ::: "memory"); }
    else if (kt < 31) { asm volatile("s_waitcnt vmcnt(0)" ::: "memory"); }
    __builtin_amdgcn_s_barrier();
    ac = (ac == 2) ? 0 : ac + 1;
  }

  // ---- epilogue ----
  // C/D frag layout: row(c) = wr*128 + mi*16 + (l>>4)*4 + reg, col(o) = wc*64 + ni*16 + (l&15)
  float psum[4] = {0.f, 0.f, 0.f, 0.f};
#pragma unroll
  for (int ni = 0; ni < 4; ++ni) {
    const int o = otile*256 + wc*64 + ni*16 + (l & 15);
    const float bqo = bq[o];
    const __bf16* klc = kl_t + (int64_t)o * 256 + wr*128 + (l >> 4)*4;
#pragma unroll
    for (int mi = 0; mi < 8; ++mi) {
      bf16x4 kv = *(const bf16x4*)(klc + mi*16);
      psum[ni] += (acc[mi][ni][0] + bqo) * (float)kv[0]
                + (acc[mi][ni][1] + bqo) * (float)kv[1]
                + (acc[mi][ni][2] + bqo) * (float)kv[2]
                + (acc[mi][ni][3] + bqo) * (float)kv[3];
    }
  }
#pragma unroll
  for (int ni = 0; ni < 4; ++ni) {  // reduce over the 4 row-groups (l>>4)
    psum[ni] += __shfl_xor(psum[ni], 16);
    psum[ni] += __shfl_xor(psum[ni], 32);
  }
  float* red = (float*)smem;  // A buf0 region; dead for reads by now
  if (l < 16) {
#pragma unroll
    for (int ni = 0; ni < 4; ++ni)
      red[wr*256 + wc*64 + ni*16 + l] = psum[ni];
  }
  __syncthreads();
  if (t < 256) {
    const float s = 0.0625f * (red[t] + red[256 + t]);  // fact * S[b, otile*256+t]
    float m = s;
    m = fmaxf(m, __shfl_xor(m, 1));
    m = fmaxf(m, __shfl_xor(m, 2));
    m = fmaxf(m, __shfl_xor(m, 4));
    const float e = __expf(s - m);
    float sum = e;
    sum += __shfl_xor(sum, 1);
    sum += __shfl_xor(sum, 2);
    sum += __shfl_xor(sum, 4);
    out[(int64_t)b*2048 + otile*256 + t] = e / sum;
  }
}

extern "C" void kernel_launch(void* const* d_in, const int* in_sizes, int n_in,
                              void* d_out, int out_size, void* d_ws, size_t ws_size,
                              hipStream_t stream) {
  (void)in_sizes; (void)n_in; (void)out_size; (void)ws_size;
  const float* q  = (const float*)d_in[0];
  const float* k  = (const float*)d_in[1];
  const float* Wq = (const float*)d_in[2];
  const float* bq = (const float*)d_in[3];
  const float* Wk = (const float*)d_in[4];
  const float* bk = (const float*)d_in[5];
  float* out = (float*)d_out;
  char* ws = (char*)d_ws;
  void* q_t  = ws;                          // 256 MiB  q bf16 TRANSPOSED [b][c][h]
  void* wq_b = ws + 268435456;              // 8 MiB    Wq bf16
  void* wk_b = ws + 268435456 + 8388608;    // 8 MiB    Wk bf16
  void* k_b  = ws + 268435456 + 16777216;   // 1 MiB    k bf16
  void* kl_t = ws + 268435456 + 17825792;   // 1 MiB    kl_t bf16 [2048 o][256 c]

  convert_kernel<<<2048, 256, 0, stream>>>(q, Wq, Wk, k, q_t, wq_b, wk_b, k_b);
  kl_kernel<<<dim3(32, 4), 256, 0, stream>>>(k_b, wk_b, bk, kl_t);
  main_kernel<<<dim3(8, 256), 512, 0, stream>>>(q_t, wq_b, bq, kl_t, out);
}